// Round 1
// baseline (3149.852 us; speedup 1.0000x reference)
//
#include <hip/hip_runtime.h>
#include <hip/hip_bf16.h>
#include <math.h>

#define B_  4
#define L_  2048
#define D_  1024
#define H_  16
#define HS_ 64
#define SCALE 0.125f   // 1/sqrt(64)

// ---------------------------------------------------------------------------
// GEMM 1: qkv = x @ W_attn + b_attn, epilogue scatters into q/k/v [B][H][L][HS]
// GEMM 2: out = y @ W_proj + b_proj, plain row-major C
// Classic 64x64 tile, BK=16, 256 threads, 4x4 micro-tile, fp32.
// ---------------------------------------------------------------------------
#define BM 64
#define BN 64
#define BK 16

__global__ __launch_bounds__(256)
void qkv_gemm(const float* __restrict__ A, const float* __restrict__ W,
              const float* __restrict__ bias, float* __restrict__ qkv)
{
    // A: [M=8192, K=1024], W: [K=1024, N=3072]
    const int M = B_ * L_;
    const int N = 3 * D_;
    const int K = D_;
    __shared__ float As[BK][BM + 4];   // transposed A tile, stride 68 (16B-aligned rows)
    __shared__ float Bs[BK][BN];

    const int tid = threadIdx.x;
    const int m0 = blockIdx.y * BM;
    const int n0 = blockIdx.x * BN;
    const int tm = (tid / 16) * 4;
    const int tn = (tid % 16) * 4;

    float acc[4][4] = {};

    for (int k0 = 0; k0 < K; k0 += BK) {
        // A tile 64x16 (1024 elems, 4/thread), coalesced on K
        {
            const int r = tid / 16, c = tid % 16;
#pragma unroll
            for (int s = 0; s < 4; ++s) {
                const int rr = r + s * 16;
                As[c][rr] = A[(size_t)(m0 + rr) * K + k0 + c];
            }
        }
        // B tile 16x64 (1024 elems, 4/thread), coalesced on N
        {
            const int r = tid / 64, c = tid % 64;
#pragma unroll
            for (int s = 0; s < 4; ++s) {
                const int rr = r + s * 4;
                Bs[rr][c] = W[(size_t)(k0 + rr) * N + n0 + c];
            }
        }
        __syncthreads();
#pragma unroll
        for (int kk = 0; kk < BK; ++kk) {
            float a[4], b[4];
#pragma unroll
            for (int u = 0; u < 4; ++u) a[u] = As[kk][tm + u];
#pragma unroll
            for (int u = 0; u < 4; ++u) b[u] = Bs[kk][tn + u];
#pragma unroll
            for (int i = 0; i < 4; ++i)
#pragma unroll
                for (int j = 0; j < 4; ++j) acc[i][j] += a[i] * b[j];
        }
        __syncthreads();
    }

    // scatter epilogue: col<1024 -> q, <2048 -> k, else v ; layout [B][H][L][HS]
#pragma unroll
    for (int i = 0; i < 4; ++i) {
        const int row = m0 + tm + i;
        const int bb = row / L_;
        const int ll = row % L_;
#pragma unroll
        for (int j = 0; j < 4; ++j) {
            const int col = n0 + tn + j;
            const float vv = acc[i][j] + bias[col];
            const int sel = col / D_;
            const int within = col % D_;
            const int hh = within / HS_;
            const int hs = within % HS_;
            const size_t dst = (size_t)sel * ((size_t)B_ * H_ * L_ * HS_) +
                               (((size_t)(bb * H_ + hh) * L_ + ll) * HS_ + hs);
            qkv[dst] = vv;
        }
    }
}

__global__ __launch_bounds__(256)
void proj_gemm(const float* __restrict__ A, const float* __restrict__ W,
               const float* __restrict__ bias, float* __restrict__ C)
{
    const int N = D_;
    const int K = D_;
    __shared__ float As[BK][BM + 4];
    __shared__ float Bs[BK][BN];

    const int tid = threadIdx.x;
    const int m0 = blockIdx.y * BM;
    const int n0 = blockIdx.x * BN;
    const int tm = (tid / 16) * 4;
    const int tn = (tid % 16) * 4;

    float acc[4][4] = {};

    for (int k0 = 0; k0 < K; k0 += BK) {
        {
            const int r = tid / 16, c = tid % 16;
#pragma unroll
            for (int s = 0; s < 4; ++s) {
                const int rr = r + s * 16;
                As[c][rr] = A[(size_t)(m0 + rr) * K + k0 + c];
            }
        }
        {
            const int r = tid / 64, c = tid % 64;
#pragma unroll
            for (int s = 0; s < 4; ++s) {
                const int rr = r + s * 4;
                Bs[rr][c] = W[(size_t)(k0 + rr) * N + n0 + c];
            }
        }
        __syncthreads();
#pragma unroll
        for (int kk = 0; kk < BK; ++kk) {
            float a[4], b[4];
#pragma unroll
            for (int u = 0; u < 4; ++u) a[u] = As[kk][tm + u];
#pragma unroll
            for (int u = 0; u < 4; ++u) b[u] = Bs[kk][tn + u];
#pragma unroll
            for (int i = 0; i < 4; ++i)
#pragma unroll
                for (int j = 0; j < 4; ++j) acc[i][j] += a[i] * b[j];
        }
        __syncthreads();
    }
#pragma unroll
    for (int i = 0; i < 4; ++i) {
        const size_t row = m0 + tm + i;
#pragma unroll
        for (int j = 0; j < 4; ++j) {
            const int col = n0 + tn + j;
            C[row * N + col] = acc[i][j] + bias[col];
        }
    }
}

// ---------------------------------------------------------------------------
// Flash-style causal attention with relative-position term.
// Srel[i,j] = dot(q[i,:], Er[L-1-i+j,:])  (j <= i), so
// score(i,j) = SCALE * dot(q[i,:], K[j,:] + Er[L-1-i+j,:])
// Block: one (b,h) + 64-query tile. 256 threads: thread = (row r=tid/4, g=tid&3).
// Key tiles of 32. Er band (95 rows) staged in LDS per key tile; the skewed
// gather becomes Ers[63 - r + jl].
// ---------------------------------------------------------------------------
#define QT 64
#define KT 32

__global__ __launch_bounds__(256)
void attn_kernel(const float* __restrict__ q, const float* __restrict__ k,
                 const float* __restrict__ v, const float* __restrict__ Er,
                 float* __restrict__ y)
{
    __shared__ float Ks[KT][68];
    __shared__ float Vs[KT][68];
    __shared__ float Ers[95][68];
    __shared__ float Ps[QT][KT + 1];

    const int tid = threadIdx.x;
    const int bh = blockIdx.y;             // 0..63
    const int qt = blockIdx.x;             // 0..31
    const int qi0 = qt * QT;
    const int bb = bh / H_;
    const int hh = bh % H_;

    const float* qp = q + (size_t)bh * L_ * HS_;
    const float* kp = k + (size_t)bh * L_ * HS_;
    const float* vp = v + (size_t)bh * L_ * HS_;

    const int r = tid >> 2;                // query row in tile, 0..63
    const int g = tid & 3;
    const int i_glob = qi0 + r;
    const int d0 = g * 16;

    // q row -> registers (reused every key tile)
    float4 qreg[16];
    {
        const float4* src = (const float4*)(qp + (size_t)i_glob * HS_);
#pragma unroll
        for (int u = 0; u < 16; ++u) qreg[u] = src[u];
    }

    float o[16];
#pragma unroll
    for (int u = 0; u < 16; ++u) o[u] = 0.f;
    float m_r = -INFINITY, l_r = 0.f;

    const int nkt = (qi0 + QT) / KT;       // 2*qt + 2 key tiles (causal)
    for (int kt = 0; kt < nkt; ++kt) {
        const int kj0 = kt * KT;
        __syncthreads();                   // previous PV done before overwrite
        // stage K,V tiles: 32x64 floats = 512 float4, 2/thread
        {
            const float4* ksrc = (const float4*)(kp + (size_t)kj0 * HS_);
            const float4* vsrc = (const float4*)(vp + (size_t)kj0 * HS_);
#pragma unroll
            for (int s = 0; s < 2; ++s) {
                const int idx = tid + s * 256;      // 0..511
                const int row = idx >> 4;
                const int c4 = idx & 15;
                *(float4*)&Ks[row][c4 * 4] = ksrc[idx];
                *(float4*)&Vs[row][c4 * 4] = vsrc[idx];
            }
            // stage Er band: rows base_lo..base_lo+94 (clamped; clamped rows only
            // feed masked scores). 1520 float4, 6/thread.
            const int base_lo = L_ - QT - qi0 + kj0;
#pragma unroll
            for (int s = 0; s < 6; ++s) {
                const int idx = tid + s * 256;
                if (idx < 95 * 16) {
                    const int row = idx >> 4;
                    const int c4 = idx & 15;
                    int m = base_lo + row;
                    m = (m < 0) ? 0 : ((m > L_ - 1) ? L_ - 1 : m);
                    *(float4*)&Ers[row][c4 * 4] =
                        ((const float4*)(Er + (size_t)m * HS_))[c4];
                }
            }
        }
        __syncthreads();

        // scores: thread handles jl = jj*4 + g (stride-4 cols -> conflict-free LDS)
        float sc[8];
#pragma unroll
        for (int jj = 0; jj < 8; ++jj) {
            const int jl = jj * 4 + g;
            const int jg = kj0 + jl;
            const int mloc = 63 - r + jl;          // in [0,94]
            float s = 0.f;
#pragma unroll
            for (int d4 = 0; d4 < 16; ++d4) {
                const float4 kk4 = *(const float4*)&Ks[jl][d4 * 4];
                const float4 ee4 = *(const float4*)&Ers[mloc][d4 * 4];
                const float4 qq = qreg[d4];
                s += qq.x * (kk4.x + ee4.x) + qq.y * (kk4.y + ee4.y) +
                     qq.z * (kk4.z + ee4.z) + qq.w * (kk4.w + ee4.w);
            }
            sc[jj] = (jg <= i_glob) ? s * SCALE : -INFINITY;
        }

        // online softmax across the 4 lanes of this row (consecutive lanes)
        float tmax = sc[0];
#pragma unroll
        for (int jj = 1; jj < 8; ++jj) tmax = fmaxf(tmax, sc[jj]);
        tmax = fmaxf(tmax, __shfl_xor(tmax, 1, 64));
        tmax = fmaxf(tmax, __shfl_xor(tmax, 2, 64));
        const float newm = fmaxf(m_r, tmax);
        const float alpha = __expf(m_r - newm);
        float psum = 0.f;
#pragma unroll
        for (int jj = 0; jj < 8; ++jj) {
            const float p = __expf(sc[jj] - newm);   // -inf -> 0
            Ps[r][jj * 4 + g] = p;
            psum += p;
        }
        psum += __shfl_xor(psum, 1, 64);
        psum += __shfl_xor(psum, 2, 64);
        l_r = l_r * alpha + psum;
        m_r = newm;
#pragma unroll
        for (int u = 0; u < 16; ++u) o[u] *= alpha;
        __syncthreads();                   // Ps visible (also keeps waves in step)

        // PV: o[r][d0..] += sum_j P[r][j] * V[j][d0..]
#pragma unroll
        for (int jl = 0; jl < KT; ++jl) {
            const float p = Ps[r][jl];
#pragma unroll
            for (int u4 = 0; u4 < 4; ++u4) {
                const float4 vv = *(const float4*)&Vs[jl][d0 + u4 * 4];
                o[u4 * 4 + 0] += p * vv.x;
                o[u4 * 4 + 1] += p * vv.y;
                o[u4 * 4 + 2] += p * vv.z;
                o[u4 * 4 + 3] += p * vv.w;
            }
        }
    }

    // write y in [B][L][H][HS] == [B,L,D] row-major
    const float inv = 1.f / l_r;
    float4* dst = (float4*)(y + ((((size_t)bb * L_ + i_glob) * H_ + hh) * HS_ + d0));
#pragma unroll
    for (int u4 = 0; u4 < 4; ++u4) {
        float4 w;
        w.x = o[u4 * 4 + 0] * inv;
        w.y = o[u4 * 4 + 1] * inv;
        w.z = o[u4 * 4 + 2] * inv;
        w.w = o[u4 * 4 + 3] * inv;
        dst[u4] = w;
    }
}

// ---------------------------------------------------------------------------
extern "C" void kernel_launch(void* const* d_in, const int* in_sizes, int n_in,
                              void* d_out, int out_size, void* d_ws, size_t ws_size,
                              hipStream_t stream)
{
    const float* x      = (const float*)d_in[0];   // [B,L,D]
    const float* W_attn = (const float*)d_in[1];   // [D,3D]
    const float* b_attn = (const float*)d_in[2];   // [3D]
    const float* W_proj = (const float*)d_in[3];   // [D,D]
    const float* b_proj = (const float*)d_in[4];   // [D]
    const float* Er     = (const float*)d_in[5];   // [L,HS]
    float* out = (float*)d_out;

    float* ws = (float*)d_ws;
    const size_t per = (size_t)B_ * H_ * L_ * HS_;   // 8388608
    float* qkv = ws;                // q | k | v, each [B][H][L][HS]
    float* qq = qkv;
    float* kk = qkv + per;
    float* vv = qkv + 2 * per;
    float* yy = qkv + 3 * per;      // [B][L][D]

    dim3 blk(256);
    dim3 g1(3 * D_ / BN, B_ * L_ / BM);      // 48 x 128
    qkv_gemm<<<g1, blk, 0, stream>>>(x, W_attn, b_attn, qkv);

    dim3 g2(L_ / QT, B_ * H_);               // 32 x 64
    attn_kernel<<<g2, blk, 0, stream>>>(qq, kk, vv, Er, yy);

    dim3 g3(D_ / BN, B_ * L_ / BM);          // 16 x 128
    proj_gemm<<<g3, blk, 0, stream>>>(yy, W_proj, b_proj, out);
}

// Round 2
// 1367.906 us; speedup vs baseline: 2.3027x; 2.3027x over previous
//
#include <hip/hip_runtime.h>
#include <hip/hip_bf16.h>
#include <math.h>

#define B_  4
#define L_  2048
#define D_  1024
#define H_  16
#define HS_ 64
#define SCALE 0.125f   // 1/sqrt(64)

typedef unsigned short ushort_t;
typedef __attribute__((ext_vector_type(8))) short short8;
typedef __attribute__((ext_vector_type(4))) float f32x4;

static __device__ __forceinline__ ushort_t f2bf(float f) {
    union { float f; unsigned int u; } cv; cv.f = f;
    unsigned int u = cv.u;
    unsigned int r = (u + 0x7FFFu + ((u >> 16) & 1u)) >> 16;   // RNE
    return (ushort_t)r;
}
static __device__ __forceinline__ float bf2f(ushort_t h) {
    union { float f; unsigned int u; } cv; cv.u = ((unsigned int)h) << 16;
    return cv.f;
}

// ---------------------------------------------------------------------------
// GEMM 1: qkv = x @ W_attn + b_attn -> scatter bf16 into q/k/v [B][H][L][HS]
// GEMM 2: out = y @ W_proj + b_proj (fp32)
// ---------------------------------------------------------------------------
#define BM 64
#define BN 64
#define BK 16

__global__ __launch_bounds__(256)
void qkv_gemm(const float* __restrict__ A, const float* __restrict__ W,
              const float* __restrict__ bias, ushort_t* __restrict__ qkv)
{
    const int N = 3 * D_;
    const int K = D_;
    __shared__ float As[BK][BM + 4];
    __shared__ float Bs[BK][BN];

    const int tid = threadIdx.x;
    const int m0 = blockIdx.y * BM;
    const int n0 = blockIdx.x * BN;
    const int tm = (tid / 16) * 4;
    const int tn = (tid % 16) * 4;

    float acc[4][4] = {};

    for (int k0 = 0; k0 < K; k0 += BK) {
        {
            const int r = tid / 16, c = tid % 16;
#pragma unroll
            for (int s = 0; s < 4; ++s) {
                const int rr = r + s * 16;
                As[c][rr] = A[(size_t)(m0 + rr) * K + k0 + c];
            }
        }
        {
            const int r = tid / 64, c = tid % 64;
#pragma unroll
            for (int s = 0; s < 4; ++s) {
                const int rr = r + s * 4;
                Bs[rr][c] = W[(size_t)(k0 + rr) * N + n0 + c];
            }
        }
        __syncthreads();
#pragma unroll
        for (int kk = 0; kk < BK; ++kk) {
            float a[4], b[4];
#pragma unroll
            for (int u = 0; u < 4; ++u) a[u] = As[kk][tm + u];
#pragma unroll
            for (int u = 0; u < 4; ++u) b[u] = Bs[kk][tn + u];
#pragma unroll
            for (int i = 0; i < 4; ++i)
#pragma unroll
                for (int j = 0; j < 4; ++j) acc[i][j] += a[i] * b[j];
        }
        __syncthreads();
    }

#pragma unroll
    for (int i = 0; i < 4; ++i) {
        const int row = m0 + tm + i;
        const int bb = row / L_;
        const int ll = row % L_;
#pragma unroll
        for (int j = 0; j < 4; ++j) {
            const int col = n0 + tn + j;
            const float vv = acc[i][j] + bias[col];
            const int sel = col / D_;
            const int within = col % D_;
            const int hh = within / HS_;
            const int hs = within % HS_;
            const size_t dst = (size_t)sel * ((size_t)B_ * H_ * L_ * HS_) +
                               (((size_t)(bb * H_ + hh) * L_ + ll) * HS_ + hs);
            qkv[dst] = f2bf(vv);
        }
    }
}

__global__ __launch_bounds__(256)
void proj_gemm(const float* __restrict__ A, const float* __restrict__ W,
               const float* __restrict__ bias, float* __restrict__ C)
{
    const int N = D_;
    const int K = D_;
    __shared__ float As[BK][BM + 4];
    __shared__ float Bs[BK][BN];

    const int tid = threadIdx.x;
    const int m0 = blockIdx.y * BM;
    const int n0 = blockIdx.x * BN;
    const int tm = (tid / 16) * 4;
    const int tn = (tid % 16) * 4;

    float acc[4][4] = {};

    for (int k0 = 0; k0 < K; k0 += BK) {
        {
            const int r = tid / 16, c = tid % 16;
#pragma unroll
            for (int s = 0; s < 4; ++s) {
                const int rr = r + s * 16;
                As[c][rr] = A[(size_t)(m0 + rr) * K + k0 + c];
            }
        }
        {
            const int r = tid / 64, c = tid % 64;
#pragma unroll
            for (int s = 0; s < 4; ++s) {
                const int rr = r + s * 4;
                Bs[rr][c] = W[(size_t)(k0 + rr) * N + n0 + c];
            }
        }
        __syncthreads();
#pragma unroll
        for (int kk = 0; kk < BK; ++kk) {
            float a[4], b[4];
#pragma unroll
            for (int u = 0; u < 4; ++u) a[u] = As[kk][tm + u];
#pragma unroll
            for (int u = 0; u < 4; ++u) b[u] = Bs[kk][tn + u];
#pragma unroll
            for (int i = 0; i < 4; ++i)
#pragma unroll
                for (int j = 0; j < 4; ++j) acc[i][j] += a[i] * b[j];
        }
        __syncthreads();
    }
#pragma unroll
    for (int i = 0; i < 4; ++i) {
        const size_t row = m0 + tm + i;
#pragma unroll
        for (int j = 0; j < 4; ++j) {
            const int col = n0 + tn + j;
            C[row * N + col] = acc[i][j] + bias[col];
        }
    }
}

// ---------------------------------------------------------------------------
// MFMA flash attention with relative positions.
// Block = (bh, 64-row q-tile), 4 waves; wave w owns q rows [w*16, w*16+16).
// Per 64-key tile: S = Q K^T (MFMA), Srel from rolling QEr chunk buffer
// (1 new 64-col chunk per iter via MFMA; skew gather = wave-private LDS read),
// online softmax (shuffle over 16 lanes), P -> LDS (A-layout), PV via MFMA.
// MFMA 16x16x32_bf16: A[m=lane&15][k=quad*8+j], B[n=lane&15][k=quad*8+j],
// C/D[row=quad*4+reg][col=lane&15]  (guide §3, m89/m91/m120 verified).
// ---------------------------------------------------------------------------
#define QT 64
#define KT 64

__global__ __launch_bounds__(256)
void attn_mfma(const ushort_t* __restrict__ q, const ushort_t* __restrict__ k,
               const ushort_t* __restrict__ v, const float* __restrict__ Er,
               float* __restrict__ y)
{
    // pitch 72 bf16 = 144 B: every row 16B-aligned for b128 frag reads
    __shared__ __align__(16) ushort_t Qs[64][72];
    __shared__ __align__(16) ushort_t Ks[64][72];
    __shared__ __align__(16) ushort_t Vt[64][72];   // [hs][key]
    __shared__ __align__(16) ushort_t EsPs[64][72]; // Er chunk rows, then P
    __shared__ __align__(16) ushort_t EBuf[64][132]; // rolling 2x64-col QEr chunks

    const int tid  = threadIdx.x;
    const int w    = tid >> 6;
    const int lane = tid & 63;
    const int quad = lane >> 4;
    const int lcol = lane & 15;
    const int bh   = blockIdx.y;
    const int qt   = (int)gridDim.x - 1 - (int)blockIdx.x;  // heavy tiles first
    const int qi0  = qt * QT;
    const int bb   = bh >> 4;       // H = 16
    const int hh   = bh & 15;
    const int cband = L_ - QT - qi0;  // band origin: m = cband + band_col

    const ushort_t* qp = q + (size_t)bh * L_ * HS_;
    const ushort_t* kp = k + (size_t)bh * L_ * HS_;
    const ushort_t* vp = v + (size_t)bh * L_ * HS_;

    const int srow = tid >> 2;          // staging: row 0..63
    const int scol = (tid & 3) * 16;    // 16 elems per thread

    // ---- prologue: stage Q tile + Er rows for chunk 0
    {
        const uint4* src = (const uint4*)(qp + (size_t)(qi0 + srow) * HS_ + scol);
        *(uint4*)&Qs[srow][scol]     = src[0];
        *(uint4*)&Qs[srow][scol + 8] = src[1];
    }
    {
        const int m = cband + srow;                 // always in [0, L-1]
        const float4* src = (const float4*)(Er + (size_t)m * HS_ + scol);
        float4 f0 = src[0], f1 = src[1], f2 = src[2], f3 = src[3];
        ushort_t o[16];
        o[0]=f2bf(f0.x); o[1]=f2bf(f0.y); o[2]=f2bf(f0.z); o[3]=f2bf(f0.w);
        o[4]=f2bf(f1.x); o[5]=f2bf(f1.y); o[6]=f2bf(f1.z); o[7]=f2bf(f1.w);
        o[8]=f2bf(f2.x); o[9]=f2bf(f2.y); o[10]=f2bf(f2.z); o[11]=f2bf(f2.w);
        o[12]=f2bf(f3.x); o[13]=f2bf(f3.y); o[14]=f2bf(f3.z); o[15]=f2bf(f3.w);
        *(uint4*)&EsPs[srow][scol]     = *(uint4*)&o[0];
        *(uint4*)&EsPs[srow][scol + 8] = *(uint4*)&o[8];
    }
    __syncthreads();

    // Q A-frags: loop-invariant
    const short8 aq0 = *(const short8*)&Qs[w * 16 + lcol][quad * 8];
    const short8 aq1 = *(const short8*)&Qs[w * 16 + lcol][32 + quad * 8];

    // chunk 0 -> EBuf cols [0,64)
    {
        f32x4 e0 = {0,0,0,0}, e1 = {0,0,0,0}, e2 = {0,0,0,0}, e3 = {0,0,0,0};
        e0 = __builtin_amdgcn_mfma_f32_16x16x32_bf16(aq0, *(const short8*)&EsPs[ 0 + lcol][quad*8],      e0, 0,0,0);
        e1 = __builtin_amdgcn_mfma_f32_16x16x32_bf16(aq0, *(const short8*)&EsPs[16 + lcol][quad*8],      e1, 0,0,0);
        e2 = __builtin_amdgcn_mfma_f32_16x16x32_bf16(aq0, *(const short8*)&EsPs[32 + lcol][quad*8],      e2, 0,0,0);
        e3 = __builtin_amdgcn_mfma_f32_16x16x32_bf16(aq0, *(const short8*)&EsPs[48 + lcol][quad*8],      e3, 0,0,0);
        e0 = __builtin_amdgcn_mfma_f32_16x16x32_bf16(aq1, *(const short8*)&EsPs[ 0 + lcol][32 + quad*8], e0, 0,0,0);
        e1 = __builtin_amdgcn_mfma_f32_16x16x32_bf16(aq1, *(const short8*)&EsPs[16 + lcol][32 + quad*8], e1, 0,0,0);
        e2 = __builtin_amdgcn_mfma_f32_16x16x32_bf16(aq1, *(const short8*)&EsPs[32 + lcol][32 + quad*8], e2, 0,0,0);
        e3 = __builtin_amdgcn_mfma_f32_16x16x32_bf16(aq1, *(const short8*)&EsPs[48 + lcol][32 + quad*8], e3, 0,0,0);
        const int rw = w * 16 + quad * 4;
#pragma unroll
        for (int reg = 0; reg < 4; ++reg) {
            EBuf[rw + reg][ 0 + lcol] = f2bf(e0[reg]);
            EBuf[rw + reg][16 + lcol] = f2bf(e1[reg]);
            EBuf[rw + reg][32 + lcol] = f2bf(e2[reg]);
            EBuf[rw + reg][48 + lcol] = f2bf(e3[reg]);
        }
    }

    f32x4 O[4];
#pragma unroll
    for (int nt = 0; nt < 4; ++nt) O[nt] = (f32x4){0, 0, 0, 0};
    float m_r[4] = {-INFINITY, -INFINITY, -INFINITY, -INFINITY};
    float l_r[4] = {0, 0, 0, 0};

    for (int kt = 0; kt <= qt; ++kt) {
        const int kj0 = kt * KT;
        __syncthreads();   // prev-iter reads of Ks/Vt/EsPs done

        // ---- stage K tile
        {
            const uint4* src = (const uint4*)(kp + (size_t)(kj0 + srow) * HS_ + scol);
            *(uint4*)&Ks[srow][scol]     = src[0];
            *(uint4*)&Ks[srow][scol + 8] = src[1];
        }
        // ---- stage V transposed
        {
            const ushort_t* src = vp + (size_t)(kj0 + srow) * HS_ + scol;
            uint4 a = *(const uint4*)src, b = *(const uint4*)(src + 8);
            ushort_t tmp[16];
            *(uint4*)&tmp[0] = a; *(uint4*)&tmp[8] = b;
#pragma unroll
            for (int u = 0; u < 16; ++u) Vt[scol + u][srow] = tmp[u];
        }
        // ---- stage Er rows for chunk kt+1 (clamped rows feed only masked cols)
        {
            int m = cband + (kt + 1) * 64 + srow;
            m = (m > L_ - 1) ? (L_ - 1) : m;
            const float4* src = (const float4*)(Er + (size_t)m * HS_ + scol);
            float4 f0 = src[0], f1 = src[1], f2 = src[2], f3 = src[3];
            ushort_t o[16];
            o[0]=f2bf(f0.x); o[1]=f2bf(f0.y); o[2]=f2bf(f0.z); o[3]=f2bf(f0.w);
            o[4]=f2bf(f1.x); o[5]=f2bf(f1.y); o[6]=f2bf(f1.z); o[7]=f2bf(f1.w);
            o[8]=f2bf(f2.x); o[9]=f2bf(f2.y); o[10]=f2bf(f2.z); o[11]=f2bf(f2.w);
            o[12]=f2bf(f3.x); o[13]=f2bf(f3.y); o[14]=f2bf(f3.z); o[15]=f2bf(f3.w);
            *(uint4*)&EsPs[srow][scol]     = *(uint4*)&o[0];
            *(uint4*)&EsPs[srow][scol + 8] = *(uint4*)&o[8];
        }
        __syncthreads();

        // ---- S = Q K^T and QEr chunk kt+1 (MFMA)
        f32x4 s0 = {0,0,0,0}, s1 = {0,0,0,0}, s2 = {0,0,0,0}, s3 = {0,0,0,0};
        f32x4 e0 = {0,0,0,0}, e1 = {0,0,0,0}, e2 = {0,0,0,0}, e3 = {0,0,0,0};
        s0 = __builtin_amdgcn_mfma_f32_16x16x32_bf16(aq0, *(const short8*)&Ks[ 0 + lcol][quad*8],        s0, 0,0,0);
        s1 = __builtin_amdgcn_mfma_f32_16x16x32_bf16(aq0, *(const short8*)&Ks[16 + lcol][quad*8],        s1, 0,0,0);
        s2 = __builtin_amdgcn_mfma_f32_16x16x32_bf16(aq0, *(const short8*)&Ks[32 + lcol][quad*8],        s2, 0,0,0);
        s3 = __builtin_amdgcn_mfma_f32_16x16x32_bf16(aq0, *(const short8*)&Ks[48 + lcol][quad*8],        s3, 0,0,0);
        s0 = __builtin_amdgcn_mfma_f32_16x16x32_bf16(aq1, *(const short8*)&Ks[ 0 + lcol][32 + quad*8],   s0, 0,0,0);
        s1 = __builtin_amdgcn_mfma_f32_16x16x32_bf16(aq1, *(const short8*)&Ks[16 + lcol][32 + quad*8],   s1, 0,0,0);
        s2 = __builtin_amdgcn_mfma_f32_16x16x32_bf16(aq1, *(const short8*)&Ks[32 + lcol][32 + quad*8],   s2, 0,0,0);
        s3 = __builtin_amdgcn_mfma_f32_16x16x32_bf16(aq1, *(const short8*)&Ks[48 + lcol][32 + quad*8],   s3, 0,0,0);
        e0 = __builtin_amdgcn_mfma_f32_16x16x32_bf16(aq0, *(const short8*)&EsPs[ 0 + lcol][quad*8],      e0, 0,0,0);
        e1 = __builtin_amdgcn_mfma_f32_16x16x32_bf16(aq0, *(const short8*)&EsPs[16 + lcol][quad*8],      e1, 0,0,0);
        e2 = __builtin_amdgcn_mfma_f32_16x16x32_bf16(aq0, *(const short8*)&EsPs[32 + lcol][quad*8],      e2, 0,0,0);
        e3 = __builtin_amdgcn_mfma_f32_16x16x32_bf16(aq0, *(const short8*)&EsPs[48 + lcol][quad*8],      e3, 0,0,0);
        e0 = __builtin_amdgcn_mfma_f32_16x16x32_bf16(aq1, *(const short8*)&EsPs[ 0 + lcol][32 + quad*8], e0, 0,0,0);
        e1 = __builtin_amdgcn_mfma_f32_16x16x32_bf16(aq1, *(const short8*)&EsPs[16 + lcol][32 + quad*8], e1, 0,0,0);
        e2 = __builtin_amdgcn_mfma_f32_16x16x32_bf16(aq1, *(const short8*)&EsPs[32 + lcol][32 + quad*8], e2, 0,0,0);
        e3 = __builtin_amdgcn_mfma_f32_16x16x32_bf16(aq1, *(const short8*)&EsPs[48 + lcol][32 + quad*8], e3, 0,0,0);

        // write chunk kt+1 into its ring slot (wave-private rows)
        {
            const int par = ((kt + 1) & 1) * 64;
            const int rw = w * 16 + quad * 4;
#pragma unroll
            for (int reg = 0; reg < 4; ++reg) {
                EBuf[rw + reg][par +  0 + lcol] = f2bf(e0[reg]);
                EBuf[rw + reg][par + 16 + lcol] = f2bf(e1[reg]);
                EBuf[rw + reg][par + 32 + lcol] = f2bf(e2[reg]);
                EBuf[rw + reg][par + 48 + lcol] = f2bf(e3[reg]);
            }
        }

        // ---- gather Srel + online softmax (rows = quad*4+reg of this wave)
        float p_[4][4];    // [nt][reg]
        float al[4];
        const float sq[4][4] = {
            {s0[0], s0[1], s0[2], s0[3]},
            {s1[0], s1[1], s1[2], s1[3]},
            {s2[0], s2[1], s2[2], s2[3]},
            {s3[0], s3[1], s3[2], s3[3]}};
#pragma unroll
        for (int reg = 0; reg < 4; ++reg) {
            const int r = w * 16 + quad * 4 + reg;   // row in q-tile
            float scr[4];
#pragma unroll
            for (int nt = 0; nt < 4; ++nt) {
                const int jl = nt * 16 + lcol;
                const int c = (63 - r + jl + kj0) & 127;
                float sv = (sq[nt][reg] + bf2f(EBuf[r][c])) * SCALE;
                if (kt == qt && jl > r) sv = -INFINITY;
                scr[nt] = sv;
            }
            float mx = fmaxf(fmaxf(scr[0], scr[1]), fmaxf(scr[2], scr[3]));
            mx = fmaxf(mx, __shfl_xor(mx, 1));
            mx = fmaxf(mx, __shfl_xor(mx, 2));
            mx = fmaxf(mx, __shfl_xor(mx, 4));
            mx = fmaxf(mx, __shfl_xor(mx, 8));
            const float nm = fmaxf(m_r[reg], mx);
            const float a_ = __expf(m_r[reg] - nm);
            m_r[reg] = nm;
            float ps = 0.f;
#pragma unroll
            for (int nt = 0; nt < 4; ++nt) {
                const float p = __expf(scr[nt] - nm);
                p_[nt][reg] = p;
                ps += p;
            }
            ps += __shfl_xor(ps, 1);
            ps += __shfl_xor(ps, 2);
            ps += __shfl_xor(ps, 4);
            ps += __shfl_xor(ps, 8);
            l_r[reg] = l_r[reg] * a_ + ps;
            al[reg] = a_;
        }
#pragma unroll
        for (int nt = 0; nt < 4; ++nt)
#pragma unroll
            for (int reg = 0; reg < 4; ++reg) O[nt][reg] *= al[reg];

        __syncthreads();   // all waves done reading Es B-frags -> reuse as Ps

        // ---- P to LDS (bf16, row-major), then PV
        {
            const int rw = w * 16 + quad * 4;
#pragma unroll
            for (int reg = 0; reg < 4; ++reg) {
                EsPs[rw + reg][ 0 + lcol] = f2bf(p_[0][reg]);
                EsPs[rw + reg][16 + lcol] = f2bf(p_[1][reg]);
                EsPs[rw + reg][32 + lcol] = f2bf(p_[2][reg]);
                EsPs[rw + reg][48 + lcol] = f2bf(p_[3][reg]);
            }
        }
        // A-frags of P are wave-private rows; same-wave DS order guarantees RAW
        const short8 ap0 = *(const short8*)&EsPs[w * 16 + lcol][quad * 8];
        const short8 ap1 = *(const short8*)&EsPs[w * 16 + lcol][32 + quad * 8];
        O[0] = __builtin_amdgcn_mfma_f32_16x16x32_bf16(ap0, *(const short8*)&Vt[ 0 + lcol][quad*8],      O[0], 0,0,0);
        O[1] = __builtin_amdgcn_mfma_f32_16x16x32_bf16(ap0, *(const short8*)&Vt[16 + lcol][quad*8],      O[1], 0,0,0);
        O[2] = __builtin_amdgcn_mfma_f32_16x16x32_bf16(ap0, *(const short8*)&Vt[32 + lcol][quad*8],      O[2], 0,0,0);
        O[3] = __builtin_amdgcn_mfma_f32_16x16x32_bf16(ap0, *(const short8*)&Vt[48 + lcol][quad*8],      O[3], 0,0,0);
        O[0] = __builtin_amdgcn_mfma_f32_16x16x32_bf16(ap1, *(const short8*)&Vt[ 0 + lcol][32 + quad*8], O[0], 0,0,0);
        O[1] = __builtin_amdgcn_mfma_f32_16x16x32_bf16(ap1, *(const short8*)&Vt[16 + lcol][32 + quad*8], O[1], 0,0,0);
        O[2] = __builtin_amdgcn_mfma_f32_16x16x32_bf16(ap1, *(const short8*)&Vt[32 + lcol][32 + quad*8], O[2], 0,0,0);
        O[3] = __builtin_amdgcn_mfma_f32_16x16x32_bf16(ap1, *(const short8*)&Vt[48 + lcol][32 + quad*8], O[3], 0,0,0);
    }

    // ---- epilogue: y[b, i, h, hs] = O / l
    float inv[4];
#pragma unroll
    for (int reg = 0; reg < 4; ++reg) inv[reg] = 1.f / l_r[reg];
#pragma unroll
    for (int nt = 0; nt < 4; ++nt) {
#pragma unroll
        for (int reg = 0; reg < 4; ++reg) {
            const int r = w * 16 + quad * 4 + reg;
            y[(((size_t)bb * L_ + qi0 + r) * H_ + hh) * HS_ + nt * 16 + lcol] =
                O[nt][reg] * inv[reg];
        }
    }
}

// ---------------------------------------------------------------------------
extern "C" void kernel_launch(void* const* d_in, const int* in_sizes, int n_in,
                              void* d_out, int out_size, void* d_ws, size_t ws_size,
                              hipStream_t stream)
{
    const float* x      = (const float*)d_in[0];   // [B,L,D]
    const float* W_attn = (const float*)d_in[1];   // [D,3D]
    const float* b_attn = (const float*)d_in[2];   // [3D]
    const float* W_proj = (const float*)d_in[3];   // [D,D]
    const float* b_proj = (const float*)d_in[4];   // [D]
    const float* Er     = (const float*)d_in[5];   // [L,HS] fp32
    float* out = (float*)d_out;

    const size_t per = (size_t)B_ * H_ * L_ * HS_;   // 8388608
    ushort_t* qb = (ushort_t*)d_ws;                  // bf16 q|k|v
    ushort_t* kb = qb + per;
    ushort_t* vb = kb + per;
    float* yy = (float*)(vb + per);                  // fp32 [B][L][D]

    dim3 blk(256);
    dim3 g1(3 * D_ / BN, B_ * L_ / BM);      // 48 x 128
    qkv_gemm<<<g1, blk, 0, stream>>>(x, W_attn, b_attn, qb);

    dim3 g2(L_ / QT, B_ * H_);               // 32 x 64
    attn_mfma<<<g2, blk, 0, stream>>>(qb, kb, vb, Er, yy);

    dim3 g3(D_ / BN, B_ * L_ / BM);          // 16 x 128
    proj_gemm<<<g3, blk, 0, stream>>>(yy, W_proj, b_proj, out);
}

// Round 3
// 582.828 us; speedup vs baseline: 5.4044x; 2.3470x over previous
//
#include <hip/hip_runtime.h>
#include <hip/hip_bf16.h>
#include <math.h>

#define B_  4
#define L_  2048
#define D_  1024
#define H_  16
#define HS_ 64
#define SCALE 0.125f   // 1/sqrt(64)

typedef unsigned short ushort_t;
typedef __attribute__((ext_vector_type(8))) short short8;
typedef __attribute__((ext_vector_type(4))) float f32x4;

static __device__ __forceinline__ ushort_t f2bf(float f) {
    union { float f; unsigned int u; } cv; cv.f = f;
    unsigned int u = cv.u;
    unsigned int r = (u + 0x7FFFu + ((u >> 16) & 1u)) >> 16;   // RNE
    return (ushort_t)r;
}
static __device__ __forceinline__ float bf2f(ushort_t h) {
    union { float f; unsigned int u; } cv; cv.u = ((unsigned int)h) << 16;
    return cv.f;
}

static __device__ __forceinline__ void gload_lds16(const ushort_t* g, ushort_t* l) {
    __builtin_amdgcn_global_load_lds(
        (const __attribute__((address_space(1))) unsigned int*)g,
        (__attribute__((address_space(3))) unsigned int*)l, 16, 0, 0);
}

// ---------------------------------------------------------------------------
// Prep kernels: fp32 -> bf16 (x), fp32 -> bf16 transposed (weights)
// ---------------------------------------------------------------------------
__global__ __launch_bounds__(256)
void conv_to_bf16(const float* __restrict__ x, ushort_t* __restrict__ xb)
{
    const size_t i = (size_t)blockIdx.x * 256 + threadIdx.x;   // 8 elems/thread
    const float4* src = (const float4*)x + i * 2;
    float4 a = src[0], b = src[1];
    ushort_t o[8] = {f2bf(a.x), f2bf(a.y), f2bf(a.z), f2bf(a.w),
                     f2bf(b.x), f2bf(b.y), f2bf(b.z), f2bf(b.w)};
    *(uint4*)(xb + i * 8) = *(uint4*)o;
}

__global__ __launch_bounds__(256)
void transpose_to_bf16(const float* __restrict__ W, ushort_t* __restrict__ Wt,
                       int K, int N)   // W:[K][N] -> Wt:[N][K]
{
    __shared__ ushort_t tile[64][65];
    const int tid = threadIdx.x;
    const int n0 = blockIdx.x * 64, k0 = blockIdx.y * 64;
#pragma unroll
    for (int s = 0; s < 16; ++s) {
        const int idx = s * 256 + tid;
        const int kl = idx >> 6, nl = idx & 63;
        tile[nl][kl] = f2bf(W[(size_t)(k0 + kl) * N + n0 + nl]);
    }
    __syncthreads();
#pragma unroll
    for (int s = 0; s < 8; ++s) {
        const int idx = s * 256 + tid;
        const int nl = idx >> 5, kc = idx & 31;
        const unsigned int vlo = tile[nl][kc * 2];
        const unsigned int vhi = tile[nl][kc * 2 + 1];
        *(unsigned int*)(Wt + (size_t)(n0 + nl) * K + k0 + kc * 2) =
            vlo | (vhi << 16);
    }
}

// ---------------------------------------------------------------------------
// m97-style bf16 MFMA GEMM: C[M][N] = A[M][K] @ Bt[N][K]^T
// 128x128 tile, BK=64, 4 waves (2x2), 16x16x32 MFMA, global_load_lds width=16.
// LDS layout [row][64] bf16 (pitch 128 B) with XOR chunk swizzle:
//   chunk slot c_lds holds global chunk c_g = c_lds ^ (row & 7)
// -> frag b128 reads spread over all 32 banks; staging stays lane-contiguous
// (global_load_lds requires LDS dst = wave-uniform base + lane*16).
// ---------------------------------------------------------------------------
__global__ __launch_bounds__(256)
void qkv_mfma(const ushort_t* __restrict__ A, const ushort_t* __restrict__ Bt,
              const float* __restrict__ bias, ushort_t* __restrict__ qkv)
{
    __shared__ __align__(16) ushort_t As[128 * 64];
    __shared__ __align__(16) ushort_t Bs[128 * 64];

    const int tid = threadIdx.x;
    const int w = tid >> 6, lane = tid & 63, quad = lane >> 4, lcol = lane & 15;
    const int wr = w >> 1, wc = w & 1;
    const int m0 = blockIdx.y * 128, n0 = blockIdx.x * 128;
    const int K = D_;

    // staging: thread t -> (row = t>>3, lds chunk = t&7, global chunk swizzled)
    const int srow = tid >> 3;
    const int cg = (tid & 7) ^ (srow & 7);
    const ushort_t* gA = A + (size_t)(m0 + srow) * K + cg * 8;
    const ushort_t* gB = Bt + (size_t)(n0 + srow) * K + cg * 8;
    ushort_t* lA = As + tid * 8;
    ushort_t* lB = Bs + tid * 8;

    // frag chunk offsets (elems): chunk (kk*4+quad) ^ (lcol&7)
    const int cs0 = ((quad) ^ (lcol & 7)) * 8;
    const int cs1 = ((4 + quad) ^ (lcol & 7)) * 8;

    f32x4 acc[4][4];
#pragma unroll
    for (int i = 0; i < 4; ++i)
#pragma unroll
        for (int j = 0; j < 4; ++j) acc[i][j] = (f32x4){0, 0, 0, 0};

    for (int k0 = 0; k0 < K; k0 += 64) {
        __syncthreads();
#pragma unroll
        for (int s = 0; s < 4; ++s) {
            gload_lds16(gA + k0 + (size_t)s * 32 * K, lA + s * 2048);
            gload_lds16(gB + k0 + (size_t)s * 32 * K, lB + s * 2048);
        }
        __syncthreads();
#pragma unroll
        for (int kk = 0; kk < 2; ++kk) {
            const int cs = kk ? cs1 : cs0;
            short8 af[4], bf[4];
#pragma unroll
            for (int i = 0; i < 4; ++i)
                af[i] = *(const short8*)&As[(wr * 64 + i * 16 + lcol) * 64 + cs];
#pragma unroll
            for (int j = 0; j < 4; ++j)
                bf[j] = *(const short8*)&Bs[(wc * 64 + j * 16 + lcol) * 64 + cs];
#pragma unroll
            for (int i = 0; i < 4; ++i)
#pragma unroll
                for (int j = 0; j < 4; ++j)
                    acc[i][j] = __builtin_amdgcn_mfma_f32_16x16x32_bf16(
                        af[i], bf[j], acc[i][j], 0, 0, 0);
        }
    }

    // epilogue: scatter bf16 into q|k|v [B][H][L][HS]
    const size_t per = (size_t)B_ * H_ * L_ * HS_;
#pragma unroll
    for (int j = 0; j < 4; ++j) {
        const int col = n0 + wc * 64 + j * 16 + lcol;
        const float bv = bias[col];
        const int sel = col >> 10;
        const int within = col & 1023;
        const int hh = within >> 6, hs = within & 63;
        ushort_t* base = qkv + (size_t)sel * per;
#pragma unroll
        for (int i = 0; i < 4; ++i) {
#pragma unroll
            for (int reg = 0; reg < 4; ++reg) {
                const int row = m0 + wr * 64 + i * 16 + quad * 4 + reg;
                const int bb = row >> 11, ll = row & 2047;
                base[(((size_t)(bb * H_ + hh)) * L_ + ll) * HS_ + hs] =
                    f2bf(acc[i][j][reg] + bv);
            }
        }
    }
}

__global__ __launch_bounds__(256)
void proj_mfma(const ushort_t* __restrict__ A, const ushort_t* __restrict__ Bt,
               const float* __restrict__ bias, float* __restrict__ C)
{
    __shared__ __align__(16) ushort_t As[128 * 64];
    __shared__ __align__(16) ushort_t Bs[128 * 64];

    const int tid = threadIdx.x;
    const int w = tid >> 6, lane = tid & 63, quad = lane >> 4, lcol = lane & 15;
    const int wr = w >> 1, wc = w & 1;
    const int m0 = blockIdx.y * 128, n0 = blockIdx.x * 128;
    const int K = D_;
    const int N = D_;

    const int srow = tid >> 3;
    const int cg = (tid & 7) ^ (srow & 7);
    const ushort_t* gA = A + (size_t)(m0 + srow) * K + cg * 8;
    const ushort_t* gB = Bt + (size_t)(n0 + srow) * K + cg * 8;
    ushort_t* lA = As + tid * 8;
    ushort_t* lB = Bs + tid * 8;

    const int cs0 = ((quad) ^ (lcol & 7)) * 8;
    const int cs1 = ((4 + quad) ^ (lcol & 7)) * 8;

    f32x4 acc[4][4];
#pragma unroll
    for (int i = 0; i < 4; ++i)
#pragma unroll
        for (int j = 0; j < 4; ++j) acc[i][j] = (f32x4){0, 0, 0, 0};

    for (int k0 = 0; k0 < K; k0 += 64) {
        __syncthreads();
#pragma unroll
        for (int s = 0; s < 4; ++s) {
            gload_lds16(gA + k0 + (size_t)s * 32 * K, lA + s * 2048);
            gload_lds16(gB + k0 + (size_t)s * 32 * K, lB + s * 2048);
        }
        __syncthreads();
#pragma unroll
        for (int kk = 0; kk < 2; ++kk) {
            const int cs = kk ? cs1 : cs0;
            short8 af[4], bf[4];
#pragma unroll
            for (int i = 0; i < 4; ++i)
                af[i] = *(const short8*)&As[(wr * 64 + i * 16 + lcol) * 64 + cs];
#pragma unroll
            for (int j = 0; j < 4; ++j)
                bf[j] = *(const short8*)&Bs[(wc * 64 + j * 16 + lcol) * 64 + cs];
#pragma unroll
            for (int i = 0; i < 4; ++i)
#pragma unroll
                for (int j = 0; j < 4; ++j)
                    acc[i][j] = __builtin_amdgcn_mfma_f32_16x16x32_bf16(
                        af[i], bf[j], acc[i][j], 0, 0, 0);
        }
    }

#pragma unroll
    for (int j = 0; j < 4; ++j) {
        const int col = n0 + wc * 64 + j * 16 + lcol;
        const float bv = bias[col];
#pragma unroll
        for (int i = 0; i < 4; ++i) {
#pragma unroll
            for (int reg = 0; reg < 4; ++reg) {
                const int row = m0 + wr * 64 + i * 16 + quad * 4 + reg;
                C[(size_t)row * N + col] = acc[i][j][reg] + bv;
            }
        }
    }
}

// ---------------------------------------------------------------------------
// MFMA flash attention with relative positions (unchanged from R2 except
// bf16 output so proj_mfma can consume it directly).
// ---------------------------------------------------------------------------
#define QT 64
#define KT 64

__global__ __launch_bounds__(256)
void attn_mfma(const ushort_t* __restrict__ q, const ushort_t* __restrict__ k,
               const ushort_t* __restrict__ v, const float* __restrict__ Er,
               ushort_t* __restrict__ y)
{
    __shared__ __align__(16) ushort_t Qs[64][72];
    __shared__ __align__(16) ushort_t Ks[64][72];
    __shared__ __align__(16) ushort_t Vt[64][72];   // [hs][key]
    __shared__ __align__(16) ushort_t EsPs[64][72]; // Er chunk rows, then P
    __shared__ __align__(16) ushort_t EBuf[64][132]; // rolling 2x64-col QEr chunks

    const int tid  = threadIdx.x;
    const int w    = tid >> 6;
    const int lane = tid & 63;
    const int quad = lane >> 4;
    const int lcol = lane & 15;
    const int bh   = blockIdx.y;
    const int qt   = (int)gridDim.x - 1 - (int)blockIdx.x;  // heavy tiles first
    const int qi0  = qt * QT;
    const int bb   = bh >> 4;
    const int hh   = bh & 15;
    const int cband = L_ - QT - qi0;

    const ushort_t* qp = q + (size_t)bh * L_ * HS_;
    const ushort_t* kp = k + (size_t)bh * L_ * HS_;
    const ushort_t* vp = v + (size_t)bh * L_ * HS_;

    const int srow = tid >> 2;
    const int scol = (tid & 3) * 16;

    {
        const uint4* src = (const uint4*)(qp + (size_t)(qi0 + srow) * HS_ + scol);
        *(uint4*)&Qs[srow][scol]     = src[0];
        *(uint4*)&Qs[srow][scol + 8] = src[1];
    }
    {
        const int m = cband + srow;
        const float4* src = (const float4*)(Er + (size_t)m * HS_ + scol);
        float4 f0 = src[0], f1 = src[1], f2 = src[2], f3 = src[3];
        ushort_t o[16];
        o[0]=f2bf(f0.x); o[1]=f2bf(f0.y); o[2]=f2bf(f0.z); o[3]=f2bf(f0.w);
        o[4]=f2bf(f1.x); o[5]=f2bf(f1.y); o[6]=f2bf(f1.z); o[7]=f2bf(f1.w);
        o[8]=f2bf(f2.x); o[9]=f2bf(f2.y); o[10]=f2bf(f2.z); o[11]=f2bf(f2.w);
        o[12]=f2bf(f3.x); o[13]=f2bf(f3.y); o[14]=f2bf(f3.z); o[15]=f2bf(f3.w);
        *(uint4*)&EsPs[srow][scol]     = *(uint4*)&o[0];
        *(uint4*)&EsPs[srow][scol + 8] = *(uint4*)&o[8];
    }
    __syncthreads();

    const short8 aq0 = *(const short8*)&Qs[w * 16 + lcol][quad * 8];
    const short8 aq1 = *(const short8*)&Qs[w * 16 + lcol][32 + quad * 8];

    {
        f32x4 e0 = {0,0,0,0}, e1 = {0,0,0,0}, e2 = {0,0,0,0}, e3 = {0,0,0,0};
        e0 = __builtin_amdgcn_mfma_f32_16x16x32_bf16(aq0, *(const short8*)&EsPs[ 0 + lcol][quad*8],      e0, 0,0,0);
        e1 = __builtin_amdgcn_mfma_f32_16x16x32_bf16(aq0, *(const short8*)&EsPs[16 + lcol][quad*8],      e1, 0,0,0);
        e2 = __builtin_amdgcn_mfma_f32_16x16x32_bf16(aq0, *(const short8*)&EsPs[32 + lcol][quad*8],      e2, 0,0,0);
        e3 = __builtin_amdgcn_mfma_f32_16x16x32_bf16(aq0, *(const short8*)&EsPs[48 + lcol][quad*8],      e3, 0,0,0);
        e0 = __builtin_amdgcn_mfma_f32_16x16x32_bf16(aq1, *(const short8*)&EsPs[ 0 + lcol][32 + quad*8], e0, 0,0,0);
        e1 = __builtin_amdgcn_mfma_f32_16x16x32_bf16(aq1, *(const short8*)&EsPs[16 + lcol][32 + quad*8], e1, 0,0,0);
        e2 = __builtin_amdgcn_mfma_f32_16x16x32_bf16(aq1, *(const short8*)&EsPs[32 + lcol][32 + quad*8], e2, 0,0,0);
        e3 = __builtin_amdgcn_mfma_f32_16x16x32_bf16(aq1, *(const short8*)&EsPs[48 + lcol][32 + quad*8], e3, 0,0,0);
        const int rw = w * 16 + quad * 4;
#pragma unroll
        for (int reg = 0; reg < 4; ++reg) {
            EBuf[rw + reg][ 0 + lcol] = f2bf(e0[reg]);
            EBuf[rw + reg][16 + lcol] = f2bf(e1[reg]);
            EBuf[rw + reg][32 + lcol] = f2bf(e2[reg]);
            EBuf[rw + reg][48 + lcol] = f2bf(e3[reg]);
        }
    }

    f32x4 O[4];
#pragma unroll
    for (int nt = 0; nt < 4; ++nt) O[nt] = (f32x4){0, 0, 0, 0};
    float m_r[4] = {-INFINITY, -INFINITY, -INFINITY, -INFINITY};
    float l_r[4] = {0, 0, 0, 0};

    for (int kt = 0; kt <= qt; ++kt) {
        const int kj0 = kt * KT;
        __syncthreads();

        {
            const uint4* src = (const uint4*)(kp + (size_t)(kj0 + srow) * HS_ + scol);
            *(uint4*)&Ks[srow][scol]     = src[0];
            *(uint4*)&Ks[srow][scol + 8] = src[1];
        }
        {
            const ushort_t* src = vp + (size_t)(kj0 + srow) * HS_ + scol;
            uint4 a = *(const uint4*)src, b = *(const uint4*)(src + 8);
            ushort_t tmp[16];
            *(uint4*)&tmp[0] = a; *(uint4*)&tmp[8] = b;
#pragma unroll
            for (int u = 0; u < 16; ++u) Vt[scol + u][srow] = tmp[u];
        }
        {
            int m = cband + (kt + 1) * 64 + srow;
            m = (m > L_ - 1) ? (L_ - 1) : m;
            const float4* src = (const float4*)(Er + (size_t)m * HS_ + scol);
            float4 f0 = src[0], f1 = src[1], f2 = src[2], f3 = src[3];
            ushort_t o[16];
            o[0]=f2bf(f0.x); o[1]=f2bf(f0.y); o[2]=f2bf(f0.z); o[3]=f2bf(f0.w);
            o[4]=f2bf(f1.x); o[5]=f2bf(f1.y); o[6]=f2bf(f1.z); o[7]=f2bf(f1.w);
            o[8]=f2bf(f2.x); o[9]=f2bf(f2.y); o[10]=f2bf(f2.z); o[11]=f2bf(f2.w);
            o[12]=f2bf(f3.x); o[13]=f2bf(f3.y); o[14]=f2bf(f3.z); o[15]=f2bf(f3.w);
            *(uint4*)&EsPs[srow][scol]     = *(uint4*)&o[0];
            *(uint4*)&EsPs[srow][scol + 8] = *(uint4*)&o[8];
        }
        __syncthreads();

        f32x4 s0 = {0,0,0,0}, s1 = {0,0,0,0}, s2 = {0,0,0,0}, s3 = {0,0,0,0};
        f32x4 e0 = {0,0,0,0}, e1 = {0,0,0,0}, e2 = {0,0,0,0}, e3 = {0,0,0,0};
        s0 = __builtin_amdgcn_mfma_f32_16x16x32_bf16(aq0, *(const short8*)&Ks[ 0 + lcol][quad*8],        s0, 0,0,0);
        s1 = __builtin_amdgcn_mfma_f32_16x16x32_bf16(aq0, *(const short8*)&Ks[16 + lcol][quad*8],        s1, 0,0,0);
        s2 = __builtin_amdgcn_mfma_f32_16x16x32_bf16(aq0, *(const short8*)&Ks[32 + lcol][quad*8],        s2, 0,0,0);
        s3 = __builtin_amdgcn_mfma_f32_16x16x32_bf16(aq0, *(const short8*)&Ks[48 + lcol][quad*8],        s3, 0,0,0);
        s0 = __builtin_amdgcn_mfma_f32_16x16x32_bf16(aq1, *(const short8*)&Ks[ 0 + lcol][32 + quad*8],   s0, 0,0,0);
        s1 = __builtin_amdgcn_mfma_f32_16x16x32_bf16(aq1, *(const short8*)&Ks[16 + lcol][32 + quad*8],   s1, 0,0,0);
        s2 = __builtin_amdgcn_mfma_f32_16x16x32_bf16(aq1, *(const short8*)&Ks[32 + lcol][32 + quad*8],   s2, 0,0,0);
        s3 = __builtin_amdgcn_mfma_f32_16x16x32_bf16(aq1, *(const short8*)&Ks[48 + lcol][32 + quad*8],   s3, 0,0,0);
        e0 = __builtin_amdgcn_mfma_f32_16x16x32_bf16(aq0, *(const short8*)&EsPs[ 0 + lcol][quad*8],      e0, 0,0,0);
        e1 = __builtin_amdgcn_mfma_f32_16x16x32_bf16(aq0, *(const short8*)&EsPs[16 + lcol][quad*8],      e1, 0,0,0);
        e2 = __builtin_amdgcn_mfma_f32_16x16x32_bf16(aq0, *(const short8*)&EsPs[32 + lcol][quad*8],      e2, 0,0,0);
        e3 = __builtin_amdgcn_mfma_f32_16x16x32_bf16(aq0, *(const short8*)&EsPs[48 + lcol][quad*8],      e3, 0,0,0);
        e0 = __builtin_amdgcn_mfma_f32_16x16x32_bf16(aq1, *(const short8*)&EsPs[ 0 + lcol][32 + quad*8], e0, 0,0,0);
        e1 = __builtin_amdgcn_mfma_f32_16x16x32_bf16(aq1, *(const short8*)&EsPs[16 + lcol][32 + quad*8], e1, 0,0,0);
        e2 = __builtin_amdgcn_mfma_f32_16x16x32_bf16(aq1, *(const short8*)&EsPs[32 + lcol][32 + quad*8], e2, 0,0,0);
        e3 = __builtin_amdgcn_mfma_f32_16x16x32_bf16(aq1, *(const short8*)&EsPs[48 + lcol][32 + quad*8], e3, 0,0,0);

        {
            const int par = ((kt + 1) & 1) * 64;
            const int rw = w * 16 + quad * 4;
#pragma unroll
            for (int reg = 0; reg < 4; ++reg) {
                EBuf[rw + reg][par +  0 + lcol] = f2bf(e0[reg]);
                EBuf[rw + reg][par + 16 + lcol] = f2bf(e1[reg]);
                EBuf[rw + reg][par + 32 + lcol] = f2bf(e2[reg]);
                EBuf[rw + reg][par + 48 + lcol] = f2bf(e3[reg]);
            }
        }

        float p_[4][4];
        float al[4];
        const float sq[4][4] = {
            {s0[0], s0[1], s0[2], s0[3]},
            {s1[0], s1[1], s1[2], s1[3]},
            {s2[0], s2[1], s2[2], s2[3]},
            {s3[0], s3[1], s3[2], s3[3]}};
#pragma unroll
        for (int reg = 0; reg < 4; ++reg) {
            const int r = w * 16 + quad * 4 + reg;
            float scr[4];
#pragma unroll
            for (int nt = 0; nt < 4; ++nt) {
                const int jl = nt * 16 + lcol;
                const int c = (63 - r + jl + kj0) & 127;
                float sv = (sq[nt][reg] + bf2f(EBuf[r][c])) * SCALE;
                if (kt == qt && jl > r) sv = -INFINITY;
                scr[nt] = sv;
            }
            float mx = fmaxf(fmaxf(scr[0], scr[1]), fmaxf(scr[2], scr[3]));
            mx = fmaxf(mx, __shfl_xor(mx, 1));
            mx = fmaxf(mx, __shfl_xor(mx, 2));
            mx = fmaxf(mx, __shfl_xor(mx, 4));
            mx = fmaxf(mx, __shfl_xor(mx, 8));
            const float nm = fmaxf(m_r[reg], mx);
            const float a_ = __expf(m_r[reg] - nm);
            m_r[reg] = nm;
            float ps = 0.f;
#pragma unroll
            for (int nt = 0; nt < 4; ++nt) {
                const float p = __expf(scr[nt] - nm);
                p_[nt][reg] = p;
                ps += p;
            }
            ps += __shfl_xor(ps, 1);
            ps += __shfl_xor(ps, 2);
            ps += __shfl_xor(ps, 4);
            ps += __shfl_xor(ps, 8);
            l_r[reg] = l_r[reg] * a_ + ps;
            al[reg] = a_;
        }
#pragma unroll
        for (int nt = 0; nt < 4; ++nt)
#pragma unroll
            for (int reg = 0; reg < 4; ++reg) O[nt][reg] *= al[reg];

        __syncthreads();

        {
            const int rw = w * 16 + quad * 4;
#pragma unroll
            for (int reg = 0; reg < 4; ++reg) {
                EsPs[rw + reg][ 0 + lcol] = f2bf(p_[0][reg]);
                EsPs[rw + reg][16 + lcol] = f2bf(p_[1][reg]);
                EsPs[rw + reg][32 + lcol] = f2bf(p_[2][reg]);
                EsPs[rw + reg][48 + lcol] = f2bf(p_[3][reg]);
            }
        }
        const short8 ap0 = *(const short8*)&EsPs[w * 16 + lcol][quad * 8];
        const short8 ap1 = *(const short8*)&EsPs[w * 16 + lcol][32 + quad * 8];
        O[0] = __builtin_amdgcn_mfma_f32_16x16x32_bf16(ap0, *(const short8*)&Vt[ 0 + lcol][quad*8],      O[0], 0,0,0);
        O[1] = __builtin_amdgcn_mfma_f32_16x16x32_bf16(ap0, *(const short8*)&Vt[16 + lcol][quad*8],      O[1], 0,0,0);
        O[2] = __builtin_amdgcn_mfma_f32_16x16x32_bf16(ap0, *(const short8*)&Vt[32 + lcol][quad*8],      O[2], 0,0,0);
        O[3] = __builtin_amdgcn_mfma_f32_16x16x32_bf16(ap0, *(const short8*)&Vt[48 + lcol][quad*8],      O[3], 0,0,0);
        O[0] = __builtin_amdgcn_mfma_f32_16x16x32_bf16(ap1, *(const short8*)&Vt[ 0 + lcol][32 + quad*8], O[0], 0,0,0);
        O[1] = __builtin_amdgcn_mfma_f32_16x16x32_bf16(ap1, *(const short8*)&Vt[16 + lcol][32 + quad*8], O[1], 0,0,0);
        O[2] = __builtin_amdgcn_mfma_f32_16x16x32_bf16(ap1, *(const short8*)&Vt[32 + lcol][32 + quad*8], O[2], 0,0,0);
        O[3] = __builtin_amdgcn_mfma_f32_16x16x32_bf16(ap1, *(const short8*)&Vt[48 + lcol][32 + quad*8], O[3], 0,0,0);
    }

    float inv[4];
#pragma unroll
    for (int reg = 0; reg < 4; ++reg) inv[reg] = 1.f / l_r[reg];
#pragma unroll
    for (int nt = 0; nt < 4; ++nt) {
#pragma unroll
        for (int reg = 0; reg < 4; ++reg) {
            const int r = w * 16 + quad * 4 + reg;
            y[(((size_t)bb * L_ + qi0 + r) * H_ + hh) * HS_ + nt * 16 + lcol] =
                f2bf(O[nt][reg] * inv[reg]);
        }
    }
}

// ---------------------------------------------------------------------------
extern "C" void kernel_launch(void* const* d_in, const int* in_sizes, int n_in,
                              void* d_out, int out_size, void* d_ws, size_t ws_size,
                              hipStream_t stream)
{
    const float* x      = (const float*)d_in[0];   // [B,L,D]
    const float* W_attn = (const float*)d_in[1];   // [D,3D]
    const float* b_attn = (const float*)d_in[2];   // [3D]
    const float* W_proj = (const float*)d_in[3];   // [D,D]
    const float* b_proj = (const float*)d_in[4];   // [D]
    const float* Er     = (const float*)d_in[5];   // [L,HS] fp32
    float* out = (float*)d_out;

    const size_t per = (size_t)B_ * H_ * L_ * HS_;   // 8388608
    ushort_t* qb  = (ushort_t*)d_ws;                 // bf16 q|k|v
    ushort_t* kb  = qb + per;
    ushort_t* vb  = kb + per;
    ushort_t* yb  = vb + per;                        // bf16 [B][L][D]
    ushort_t* xb  = yb + per;                        // bf16 x
    ushort_t* wat = xb + per;                        // W_attn^T bf16 [3072][1024]
    ushort_t* wpt = wat + (size_t)3 * D_ * D_;       // W_proj^T bf16 [1024][1024]

    dim3 blk(256);

    conv_to_bf16<<<dim3((B_ * L_ * D_) / 2048), blk, 0, stream>>>(x, xb);
    transpose_to_bf16<<<dim3(3 * D_ / 64, D_ / 64), blk, 0, stream>>>(W_attn, wat, D_, 3 * D_);
    transpose_to_bf16<<<dim3(D_ / 64, D_ / 64), blk, 0, stream>>>(W_proj, wpt, D_, D_);

    qkv_mfma<<<dim3(3 * D_ / 128, B_ * L_ / 128), blk, 0, stream>>>(xb, wat, b_attn, qb);

    attn_mfma<<<dim3(L_ / QT, B_ * H_), blk, 0, stream>>>(qb, kb, vb, Er, yb);

    proj_mfma<<<dim3(D_ / 128, B_ * L_ / 128), blk, 0, stream>>>(yb, wpt, b_proj, out);
}